// Round 11
// baseline (2585.431 us; speedup 1.0000x reference)
//
#include <hip/hip_runtime.h>
#include <math.h>

#define B_   32
#define N_   1024
#define C_   4096
#define HC_  2048
#define D_   64
#define NT_  32768           // B*N tokens
#define KS_  4               // K splits for the P-GEMM
#define KC_  (HC_ / KS_)     // 512 columns per split
#define BKC_ 32              // K-chunk per staging step

// Diagnostic repetition counts (bijective block permutation per rep; final
// state identical to 1 rep).  REVERT TO 1 AFTER MEASUREMENT.
#define R3_  8
#define R1_  12
#define R2A_ 96
#define R2B_ 512
#define R45_ 5

__device__ __forceinline__ float4 ld4(const float* p) {
    return *reinterpret_cast<const float4*>(p);
}

// ---------------------------------------------------------------------------
// K3f: fused GEMM + lower-half stats.  M128 tiles.  grid 1024.
// ---------------------------------------------------------------------------
__global__ __launch_bounds__(256) void k3_fused(
        const float* __restrict__ x, const float* __restrict__ lnw,
        const float* __restrict__ w1, float* __restrict__ Pp,
        float* __restrict__ spq) {
    __shared__ float As[BKC_ * 128];   // 16 KB
    __shared__ float Bsm[BKC_ * D_];   // 8 KB

    const int t = threadIdx.x;
    const int rt = t & 31;             // row tile: rows rt*4 .. rt*4+3
    const int dt = t >> 5;             // d tile: cols dt*8 .. dt*8+7
    const int lrow = t >> 3;           // loader row (0..31)
    const int lq = t & 7;              // loader k-quad

#pragma unroll 1
    for (int rep = 0; rep < R3_; ++rep) {
        const int vb = (blockIdx.x + rep * 509) & 1023;
        const int mt = vb & 255;       // M tile (128 rows)
        const int ks = vb >> 8;        // K split (0..3)
        const int T0 = mt * 128;
        const int kbase = ks * KC_;

        float acc[32];
#pragma unroll
        for (int i = 0; i < 32; ++i) acc[i] = 0.f;
        float sRow[4], qRow[4];
#pragma unroll
        for (int p = 0; p < 4; ++p) { sRow[p] = 0.f; qRow[p] = 0.f; }

        float4 xv[4];
        float4 wv1, wv2;
        float lw1, lw2;
        {   // prologue: load chunk 0
            const int k0 = kbase;
#pragma unroll
            for (int p = 0; p < 4; ++p)
                xv[p] = ld4(x + (size_t)(T0 + lrow + 32 * p) * C_
                            + k0 + lq * 4);
            const float4* s4 = reinterpret_cast<const float4*>(
                w1 + (size_t)k0 * D_);
            wv1 = s4[t]; wv2 = s4[256 + t];
            lw1 = lnw[k0 + (t >> 4)];
            lw2 = lnw[k0 + 16 + (t >> 4)];
        }

#pragma unroll 1
        for (int kc = 0; kc < KC_ / BKC_; ++kc) {
#pragma unroll
            for (int p = 0; p < 4; ++p) {
                const float4 v = xv[p];
                const int r = lrow + 32 * p;
                const int gq = r >> 2, rm = r & 3;
                const int kb = 4 * lq;
#pragma unroll
                for (int j = 0; j < 4; ++j) {
                    const float c = (j == 0) ? v.x : (j == 1) ? v.y
                                  : (j == 2) ? v.z : v.w;
                    const int p5 = (5 * lq + j) & 31;
                    As[(kb + j) * 128 + (((gq ^ p5) << 2) + rm)] = c;
                }
                sRow[p] += (v.x + v.y) + (v.z + v.w);
                qRow[p] = fmaf(v.x, v.x, fmaf(v.y, v.y,
                          fmaf(v.z, v.z, fmaf(v.w, v.w, qRow[p]))));
            }
            {
                float4 v1 = wv1, v2 = wv2;
                v1.x *= lw1; v1.y *= lw1; v1.z *= lw1; v1.w *= lw1;
                v2.x *= lw2; v2.y *= lw2; v2.z *= lw2; v2.w *= lw2;
                float4* b4 = reinterpret_cast<float4*>(Bsm);
                b4[t] = v1;
                b4[256 + t] = v2;
            }
            __syncthreads();
            if (kc + 1 < KC_ / BKC_) {
                const int k1 = kbase + (kc + 1) * BKC_;
#pragma unroll
                for (int p = 0; p < 4; ++p)
                    xv[p] = ld4(x + (size_t)(T0 + lrow + 32 * p) * C_
                                + k1 + lq * 4);
                const float4* s4 = reinterpret_cast<const float4*>(
                    w1 + (size_t)k1 * D_);
                wv1 = s4[t]; wv2 = s4[256 + t];
                lw1 = lnw[k1 + (t >> 4)];
                lw2 = lnw[k1 + 16 + (t >> 4)];
            }
#pragma unroll 8
            for (int k = 0; k < BKC_; ++k) {
                const int p5 = (5 * (k >> 2) + (k & 3)) & 31;
                const float4 a4 = *reinterpret_cast<const float4*>(
                    As + k * 128 + ((rt ^ p5) << 2));
                const float* br = Bsm + k * D_ + dt * 8;
                const float4 b0 = ld4(br), b1v = ld4(br + 4);
                const float av[4] = {a4.x, a4.y, a4.z, a4.w};
                const float bv[8] = {b0.x, b0.y, b0.z, b0.w,
                                     b1v.x, b1v.y, b1v.z, b1v.w};
#pragma unroll
                for (int ri = 0; ri < 4; ++ri)
#pragma unroll
                    for (int cj = 0; cj < 8; ++cj)
                        acc[ri * 8 + cj] =
                            fmaf(av[ri], bv[cj], acc[ri * 8 + cj]);
            }
            __syncthreads();
        }
#pragma unroll
        for (int ri = 0; ri < 4; ++ri) {
            float* dst = Pp + ((size_t)ks * NT_ + T0 + rt * 4 + ri) * D_
                         + dt * 8;
            *reinterpret_cast<float4*>(dst) = make_float4(
                acc[ri * 8 + 0], acc[ri * 8 + 1], acc[ri * 8 + 2],
                acc[ri * 8 + 3]);
            *reinterpret_cast<float4*>(dst + 4) = make_float4(
                acc[ri * 8 + 4], acc[ri * 8 + 5], acc[ri * 8 + 6],
                acc[ri * 8 + 7]);
        }
#pragma unroll
        for (int p = 0; p < 4; ++p) {
            float s = sRow[p], q = qRow[p];
            s += __shfl_xor(s, 1); q += __shfl_xor(q, 1);
            s += __shfl_xor(s, 2); q += __shfl_xor(q, 2);
            s += __shfl_xor(s, 4); q += __shfl_xor(q, 4);
            if (lq == 0) {
                const size_t r = (size_t)(T0 + lrow + 32 * p) * 8;
                spq[r + ks] = s;
                spq[r + 4 + ks] = q;
            }
        }
        __syncthreads();
    }
}

// ---------------------------------------------------------------------------
// K1u: upper-half stats + g-accum.  grid 1024 x 32 rows.
// ---------------------------------------------------------------------------
__global__ __launch_bounds__(256) void k1_upper(
        const float* __restrict__ x, const float* __restrict__ lnw,
        const float* __restrict__ lnb, const float* __restrict__ spq,
        float* __restrict__ muv, float* __restrict__ rsv,
        float* __restrict__ part) {
    __shared__ float sh[4][HC_];     // 32 KB
    const int t = threadIdx.x;
    const int lane = t & 63, w = t >> 6;

    float4 wv[8], bv[8];
#pragma unroll
    for (int m = 0; m < 8; ++m) {
        wv[m] = ld4(lnw + HC_ + (m * 64 + lane) * 4);
        bv[m] = ld4(lnb + HC_ + (m * 64 + lane) * 4);
    }

#pragma unroll 1
    for (int rep = 0; rep < R1_; ++rep) {
        const int vb = (blockIdx.x + rep * 511) & 1023;
        const int b = vb >> 5;
        const int g = vb & 31;
        float4 gacc[8];
#pragma unroll
        for (int m = 0; m < 8; ++m)
            gacc[m] = make_float4(0.f, 0.f, 0.f, 0.f);

        for (int i = 0; i < 8; ++i) {
            const int tok = b * N_ + g * 32 + w * 8 + i;
            const float* row = x + (size_t)tok * C_ + HC_;
            float4 v[8];
            float s = 0.f, q = 0.f;
#pragma unroll
            for (int m = 0; m < 8; ++m) {
                v[m] = ld4(row + (m * 64 + lane) * 4);
                s += (v[m].x + v[m].y) + (v[m].z + v[m].w);
                q = fmaf(v[m].x, v[m].x, fmaf(v[m].y, v[m].y,
                    fmaf(v[m].z, v[m].z, fmaf(v[m].w, v[m].w, q))));
            }
#pragma unroll
            for (int o = 1; o < 64; o <<= 1) {
                s += __shfl_xor(s, o);
                q += __shfl_xor(q, o);
            }
            const float4 s0 = ld4(spq + (size_t)tok * 8);
            const float4 q0 = ld4(spq + (size_t)tok * 8 + 4);
            const float S = s + (s0.x + s0.y) + (s0.z + s0.w);
            const float Q = q + (q0.x + q0.y) + (q0.z + q0.w);
            const float mu = S * (1.f / C_);
            const float rs = rsqrtf(Q * (1.f / C_) - mu * mu + 1e-5f);
            if (lane == 0) {
                muv[tok] = mu;
                rsv[tok] = rs;
            }
#pragma unroll
            for (int m = 0; m < 8; ++m) {
                gacc[m].x += (v[m].x - mu) * rs * wv[m].x + bv[m].x;
                gacc[m].y += (v[m].y - mu) * rs * wv[m].y + bv[m].y;
                gacc[m].z += (v[m].z - mu) * rs * wv[m].z + bv[m].z;
                gacc[m].w += (v[m].w - mu) * rs * wv[m].w + bv[m].w;
            }
        }
#pragma unroll
        for (int m = 0; m < 8; ++m)
            *reinterpret_cast<float4*>(&sh[w][(m * 64 + lane) * 4]) = gacc[m];
        __syncthreads();
        float* pp = part + (size_t)vb * HC_;
#pragma unroll
        for (int m = 0; m < 8; ++m) {
            const int j = (m * 64 + lane) * 4;
            const float4 a0 = ld4(&sh[0][j]);
            const float4 a1 = ld4(&sh[1][j]);
            const float4 a2 = ld4(&sh[2][j]);
            const float4 a3 = ld4(&sh[3][j]);
            float4 r;
            r.x = (a0.x + a1.x) + (a2.x + a3.x);
            r.y = (a0.y + a1.y) + (a2.y + a3.y);
            r.z = (a0.z + a1.z) + (a2.z + a3.z);
            r.w = (a0.w + a1.w) + (a2.w + a3.w);
            if (w == (m & 3))
                *reinterpret_cast<float4*>(pp + j) = r;
        }
        __syncthreads();
    }
}

// ---------------------------------------------------------------------------
// K2a: fold partial-reduce + partial GEMVs.  grid 264.
// ---------------------------------------------------------------------------
__global__ __launch_bounds__(256) void k2a_part(
        const float* __restrict__ part, const float* __restrict__ w1,
        const float* __restrict__ lnw, const float* __restrict__ lnb,
        float* __restrict__ gpart, float* __restrict__ Wpart,
        float* __restrict__ Bpart) {
    __shared__ float Gs[256];
    __shared__ float red[512];
    const int t = threadIdx.x;
    const int d = t & 63, s = t >> 6;

#pragma unroll 1
    for (int rep = 0; rep < R2A_; ++rep) {
        const int blk = (blockIdx.x + rep * 131) % 264;
        if (blk < 256) {
            const int b = blk >> 3, jq = blk & 7;
            const int j = jq * 256 + t;
            float a = 0.f;
            for (int k = 0; k < 32; ++k)
                a += part[(size_t)(b * 32 + k) * HC_ + j];
            Gs[t] = a;
            __syncthreads();
            float acc = 0.f;
            const int j0 = jq * 256 + s * 64;
            for (int jj = 0; jj < 64; ++jj)
                acc = fmaf(Gs[s * 64 + jj],
                           w1[(size_t)(HC_ + j0 + jj) * D_ + d], acc);
            red[s * 64 + d] = acc;
            __syncthreads();
            if (s == 0)
                gpart[(size_t)blk * 64 + d] =
                    red[d] + red[64 + d] + red[128 + d] + red[192 + d];
        } else {
            const int wq = blk - 256;
            const int c0 = wq * 256 + s * 64;
            float a = 0.f, c2 = 0.f;
            for (int c = c0; c < c0 + 64; ++c) {
                const float wvv = w1[(size_t)c * D_ + d];
                a = fmaf(lnw[c], wvv, a);
                c2 = fmaf(lnb[c], wvv, c2);
            }
            red[s * 64 + d] = a;
            red[256 + s * 64 + d] = c2;
            __syncthreads();
            if (s == 0) {
                Wpart[wq * 64 + d] =
                    red[d] + red[64 + d] + red[128 + d] + red[192 + d];
                Bpart[wq * 64 + d] = red[256 + d] + red[320 + d]
                                   + red[384 + d] + red[448 + d];
            }
        }
        __syncthreads();
    }
}

// ---------------------------------------------------------------------------
// K2b: final reduce.  grid 33, block 64.
// ---------------------------------------------------------------------------
__global__ __launch_bounds__(64) void k2b_final(
        const float* __restrict__ gpart, const float* __restrict__ Wpart,
        const float* __restrict__ Bpart, float* __restrict__ gterm,
        float* __restrict__ W1s, float* __restrict__ Bs) {
    const int d = threadIdx.x;
#pragma unroll 1
    for (int rep = 0; rep < R2B_; ++rep) {
        const int b = (blockIdx.x + rep * 16) % 33;
        if (b < B_) {
            float a = 0.f;
#pragma unroll
            for (int q = 0; q < 8; ++q)
                a += gpart[(size_t)(b * 8 + q) * 64 + d];
            gterm[b * D_ + d] = a * (1.f / N_);
        } else {
            float a = 0.f, c2 = 0.f;
#pragma unroll
            for (int q = 0; q < 8; ++q) {
                a += Wpart[q * 64 + d];
                c2 += Bpart[q * 64 + d];
            }
            W1s[d] = a;
            Bs[d] = c2;
        }
    }
}

// ---------------------------------------------------------------------------
// K45: per-token decision + masked copy.  grid 8192.
// ---------------------------------------------------------------------------
__global__ __launch_bounds__(256) void k45_decide_mask(
        const float* __restrict__ Pp, const float* __restrict__ muv,
        const float* __restrict__ rsv, const float* __restrict__ gterm,
        const float* __restrict__ W1s, const float* __restrict__ Bs,
        const float* __restrict__ b1, const float* __restrict__ w2,
        const float* __restrict__ b2, const float* __restrict__ gum,
        const float* __restrict__ x, float* __restrict__ out) {
    const int t = threadIdx.x;
    const int lane = t & 63, w = t >> 6;

#pragma unroll 1
    for (int rep = 0; rep < R45_; ++rep) {
        const int vb = (blockIdx.x + rep * 2731) & 8191;
        const int token = vb * 4 + w;
        const int b = token >> 10;

        const float2 gv = *reinterpret_cast<const float2*>(gum + token * 2);
        float p = 0.f;
#pragma unroll
        for (int s = 0; s < KS_; ++s)
            p += Pp[((size_t)s * NT_ + token) * D_ + lane];

        const float mu = muv[token], rs = rsv[token];
        float h = rs * (p - mu * W1s[lane]) + Bs[lane] + gterm[b * D_ + lane]
                  + b1[lane];
        h = 0.5f * h * (1.f + erff(h * 0.70710678118654752f));
        const float2 w2v = *reinterpret_cast<const float2*>(w2 + lane * 2);
        float l0 = h * w2v.x;
        float l1 = h * w2v.y;
#pragma unroll
        for (int o = 1; o < 64; o <<= 1) {
            l0 += __shfl_xor(l0, o);
            l1 += __shfl_xor(l1, o);
        }
        const float z0 = l0 + b2[0] + gv.x;
        const float z1 = l1 + b2[1] + gv.y;

        float4* dst = reinterpret_cast<float4*>(out + (size_t)token * C_);
        if (z0 >= z1) {
            const float4* src =
                reinterpret_cast<const float4*>(x + (size_t)token * C_);
#pragma unroll
            for (int c = 0; c < 16; ++c)
                dst[c * 64 + lane] = src[c * 64 + lane];
        } else {
            const float4 z = make_float4(0.f, 0.f, 0.f, 0.f);
#pragma unroll
            for (int c = 0; c < 16; ++c)
                dst[c * 64 + lane] = z;
        }
    }
}

// ---------------------------------------------------------------------------
extern "C" void kernel_launch(void* const* d_in, const int* in_sizes, int n_in,
                              void* d_out, int out_size, void* d_ws,
                              size_t ws_size, hipStream_t stream) {
    const float* x   = (const float*)d_in[0];
    const float* gum = (const float*)d_in[1];
    const float* lnw = (const float*)d_in[2];
    const float* lnb = (const float*)d_in[3];
    const float* w1  = (const float*)d_in[4];
    const float* b1  = (const float*)d_in[5];
    const float* w2  = (const float*)d_in[6];
    const float* b2  = (const float*)d_in[7];
    float* out = (float*)d_out;

    float* wsf   = (float*)d_ws;
    float* Pp    = wsf;                                   // 4*32768*64
    float* muv   = Pp + (size_t)KS_ * NT_ * D_;           // 32768
    float* rsv   = muv + NT_;                             // 32768
    float* part  = rsv + NT_;                             // 1024*2048
    float* gterm = part + (size_t)1024 * HC_;             // 32*64
    float* W1s   = gterm + B_ * D_;                       // 64
    float* Bs    = W1s + D_;                              // 64
    float* spq   = Bs + D_;                               // 32768*8
    float* gpart = spq + (size_t)NT_ * 8;                 // 256*64
    float* Wpart = gpart + 256 * 64;                      // 8*64
    float* Bpart = Wpart + 8 * 64;                        // 8*64

    k3_fused<<<KS_ * 256, 256, 0, stream>>>(x, lnw, w1, Pp, spq);
    k1_upper<<<1024, 256, 0, stream>>>(x, lnw, lnb, spq, muv, rsv, part);
    k2a_part<<<264, 256, 0, stream>>>(part, w1, lnw, lnb,
                                      gpart, Wpart, Bpart);
    k2b_final<<<33, 64, 0, stream>>>(gpart, Wpart, Bpart, gterm, W1s, Bs);
    k45_decide_mask<<<NT_ / 4, 256, 0, stream>>>(Pp, muv, rsv, gterm, W1s,
                                                 Bs, b1, w2, b2, gum, x, out);
}

// Round 12
// 370.780 us; speedup vs baseline: 6.9729x; 6.9729x over previous
//
#include <hip/hip_runtime.h>
#include <math.h>

#define B_   32
#define N_   1024
#define C_   4096
#define HC_  2048
#define D_   64
#define NT_  32768           // B*N tokens
#define BKC_ 32              // K-chunk per staging step
#define NCH_ (HC_ / BKC_)    // 64 chunks
#define AST_ 68              // As row stride (64 rows + 4 pad)

__device__ __forceinline__ float4 ld4(const float* p) {
    return *reinterpret_cast<const float4*>(p);
}

// ---------------------------------------------------------------------------
// MK1: fused GEMM (full K=2048, KS=1) + LN stats + upper-half g-accum.
// grid 512 (M64 tiles), block 256.
// Phase G: P[t,d] = sum_c x[t,c]*(lnw[c]*w1[c,d]) for 64 rows; lower-half
//          per-row sum/sumsq accumulated from staging regs -> sLow/qLow LDS.
// Phase U: read upper half of the SAME rows, finalize mu/rs, write muv/rsv,
//          accumulate normalized-upper partials -> part[block].
// LDS: 32KB union (GEMM dbuf buffers / sh[4][2048]) + sLow/qLow.
// ---------------------------------------------------------------------------
__global__ __launch_bounds__(256) void mk1(
        const float* __restrict__ x, const float* __restrict__ lnw,
        const float* __restrict__ lnb, const float* __restrict__ w1,
        float* __restrict__ Pp, float* __restrict__ muv,
        float* __restrict__ rsv, float* __restrict__ part) {
    __shared__ float smem[8704];       // 34 KB union
    __shared__ float sLow[64], qLow[64];

    float* As0 = smem;                 // 32*68 = 2176
    float* As1 = smem + 2176;
    float* Bs0 = smem + 4352;          // 32*64 = 2048
    float* Bs1 = smem + 6400;

    const int t = threadIdx.x;
    const int tid = blockIdx.x;
    const int T0 = tid * 64;           // first row (token)
    const int rt = t & 15;             // row-quad: rows rt*4 .. rt*4+3
    const int dt = t >> 4;             // col-quad: cols dt*4 .. dt*4+3
    const int row = t >> 2;            // loader row (0..63)
    const int fq = t & 3;              // loader float4 slot
    const int lane = t & 63, w = t >> 6;

    // ===================== Phase G: GEMM + lower stats =====================
    float acc[16];
#pragma unroll
    for (int i = 0; i < 16; ++i) acc[i] = 0.f;
    float sR = 0.f, qR = 0.f;

    float4 xv1, xv2, wv1, wv2;
    float lw1, lw2;
    {   // prologue: chunk 0
        const float* rp = x + (size_t)(T0 + row) * C_;
        xv1 = ld4(rp + fq * 4);
        xv2 = ld4(rp + 16 + fq * 4);
        const float4* s4 = reinterpret_cast<const float4*>(w1);
        wv1 = s4[t]; wv2 = s4[256 + t];
        lw1 = lnw[t >> 4];
        lw2 = lnw[16 + (t >> 4)];
    }

#pragma unroll 1
    for (int c = 0; c < NCH_; ++c) {
        float* Ab = (c & 1) ? As1 : As0;
        float* Bb = (c & 1) ? Bs1 : Bs0;
        // stage A (k-major, stride 68) + stats from regs
        {
            const int kb1 = fq * 4, kb2 = 16 + fq * 4;
            Ab[(kb1 + 0) * AST_ + row] = xv1.x;
            Ab[(kb1 + 1) * AST_ + row] = xv1.y;
            Ab[(kb1 + 2) * AST_ + row] = xv1.z;
            Ab[(kb1 + 3) * AST_ + row] = xv1.w;
            Ab[(kb2 + 0) * AST_ + row] = xv2.x;
            Ab[(kb2 + 1) * AST_ + row] = xv2.y;
            Ab[(kb2 + 2) * AST_ + row] = xv2.z;
            Ab[(kb2 + 3) * AST_ + row] = xv2.w;
            sR += ((xv1.x + xv1.y) + (xv1.z + xv1.w))
                + ((xv2.x + xv2.y) + (xv2.z + xv2.w));
            qR = fmaf(xv1.x, xv1.x, fmaf(xv1.y, xv1.y,
                 fmaf(xv1.z, xv1.z, fmaf(xv1.w, xv1.w, qR))));
            qR = fmaf(xv2.x, xv2.x, fmaf(xv2.y, xv2.y,
                 fmaf(xv2.z, xv2.z, fmaf(xv2.w, xv2.w, qR))));
        }
        // stage B (lnw-folded)
        {
            float4 v1 = wv1, v2 = wv2;
            v1.x *= lw1; v1.y *= lw1; v1.z *= lw1; v1.w *= lw1;
            v2.x *= lw2; v2.y *= lw2; v2.z *= lw2; v2.w *= lw2;
            float4* b4 = reinterpret_cast<float4*>(Bb);
            b4[t] = v1;
            b4[256 + t] = v2;
        }
        __syncthreads();   // single barrier per chunk (dbuf)
        // prefetch next chunk (overlaps FMA loop)
        if (c + 1 < NCH_) {
            const int k1 = (c + 1) * BKC_;
            const float* rp = x + (size_t)(T0 + row) * C_ + k1;
            xv1 = ld4(rp + fq * 4);
            xv2 = ld4(rp + 16 + fq * 4);
            const float4* s4 = reinterpret_cast<const float4*>(
                w1 + (size_t)k1 * D_);
            wv1 = s4[t]; wv2 = s4[256 + t];
            lw1 = lnw[k1 + (t >> 4)];
            lw2 = lnw[k1 + 16 + (t >> 4)];
        }
        // FMA loop: per k = 1 b128 A (2-way max) + 1 b128 B (broadcast)
#pragma unroll
        for (int k = 0; k < BKC_; ++k) {
            const float4 a4 = *reinterpret_cast<const float4*>(
                Ab + k * AST_ + rt * 4);
            const float4 b4 = *reinterpret_cast<const float4*>(
                Bb + k * 64 + dt * 4);
            const float av[4] = {a4.x, a4.y, a4.z, a4.w};
            const float bv[4] = {b4.x, b4.y, b4.z, b4.w};
#pragma unroll
            for (int ri = 0; ri < 4; ++ri)
#pragma unroll
                for (int cj = 0; cj < 4; ++cj)
                    acc[ri * 4 + cj] =
                        fmaf(av[ri], bv[cj], acc[ri * 4 + cj]);
        }
    }
    // write P: rows rt*4+ri, cols dt*4..+3
#pragma unroll
    for (int ri = 0; ri < 4; ++ri) {
        float* dst = Pp + (size_t)(T0 + rt * 4 + ri) * D_ + dt * 4;
        *reinterpret_cast<float4*>(dst) = make_float4(
            acc[ri * 4 + 0], acc[ri * 4 + 1],
            acc[ri * 4 + 2], acc[ri * 4 + 3]);
    }
    // lower-stats reduce: 4 loader threads per row (lanes row*4+fq)
    sR += __shfl_xor(sR, 1); qR += __shfl_xor(qR, 1);
    sR += __shfl_xor(sR, 2); qR += __shfl_xor(qR, 2);
    if (fq == 0) { sLow[row] = sR; qLow[row] = qR; }
    __syncthreads();

    // ===================== Phase U: upper stats + g-accum ==================
    float4 wv[8], bv[8], gacc[8];
#pragma unroll
    for (int m = 0; m < 8; ++m) {
        wv[m] = ld4(lnw + HC_ + (m * 64 + lane) * 4);
        bv[m] = ld4(lnb + HC_ + (m * 64 + lane) * 4);
        gacc[m] = make_float4(0.f, 0.f, 0.f, 0.f);
    }
    for (int i = 0; i < 16; ++i) {
        const int r = w * 16 + i;      // row in tile
        const int tok = T0 + r;
        const float* rowp = x + (size_t)tok * C_ + HC_;
        float4 v[8];
        float s = 0.f, q = 0.f;
#pragma unroll
        for (int m = 0; m < 8; ++m) {
            v[m] = ld4(rowp + (m * 64 + lane) * 4);
            s += (v[m].x + v[m].y) + (v[m].z + v[m].w);
            q = fmaf(v[m].x, v[m].x, fmaf(v[m].y, v[m].y,
                fmaf(v[m].z, v[m].z, fmaf(v[m].w, v[m].w, q))));
        }
#pragma unroll
        for (int o = 1; o < 64; o <<= 1) {
            s += __shfl_xor(s, o);
            q += __shfl_xor(q, o);
        }
        const float S = s + sLow[r];
        const float Q = q + qLow[r];
        const float mu = S * (1.f / C_);
        const float rs = rsqrtf(Q * (1.f / C_) - mu * mu + 1e-5f);
        if (lane == 0) {
            muv[tok] = mu;
            rsv[tok] = rs;
        }
#pragma unroll
        for (int m = 0; m < 8; ++m) {
            gacc[m].x += (v[m].x - mu) * rs * wv[m].x + bv[m].x;
            gacc[m].y += (v[m].y - mu) * rs * wv[m].y + bv[m].y;
            gacc[m].z += (v[m].z - mu) * rs * wv[m].z + bv[m].z;
            gacc[m].w += (v[m].w - mu) * rs * wv[m].w + bv[m].w;
        }
    }
    // cross-wave reduction via smem (sh[4][2048]); GEMM buffers are dead
    float (*sh)[HC_] = reinterpret_cast<float(*)[HC_]>(smem);
#pragma unroll
    for (int m = 0; m < 8; ++m)
        *reinterpret_cast<float4*>(&sh[w][(m * 64 + lane) * 4]) = gacc[m];
    __syncthreads();
    float* pp = part + (size_t)tid * HC_;
#pragma unroll
    for (int m = 0; m < 8; ++m) {
        const int j = (m * 64 + lane) * 4;
        const float4 a0 = ld4(&sh[0][j]);
        const float4 a1 = ld4(&sh[1][j]);
        const float4 a2 = ld4(&sh[2][j]);
        const float4 a3 = ld4(&sh[3][j]);
        float4 r;
        r.x = (a0.x + a1.x) + (a2.x + a3.x);
        r.y = (a0.y + a1.y) + (a2.y + a3.y);
        r.z = (a0.z + a1.z) + (a2.z + a3.z);
        r.w = (a0.w + a1.w) + (a2.w + a3.w);
        if (w == (m & 3))
            *reinterpret_cast<float4*>(pp + j) = r;
    }
}

// ---------------------------------------------------------------------------
// K2a: fold partial-reduce + partial GEMVs.  grid 264, block 256.
// blocks 0..255: (b, jq) — sum 16 partials (512 part rows) then GEMV.
// blocks 256..263: Wpart/Bpart over 256 c each.
// ---------------------------------------------------------------------------
__global__ __launch_bounds__(256) void k2a_part(
        const float* __restrict__ part, const float* __restrict__ w1,
        const float* __restrict__ lnw, const float* __restrict__ lnb,
        float* __restrict__ gpart, float* __restrict__ Wpart,
        float* __restrict__ Bpart) {
    __shared__ float Gs[256];
    __shared__ float red[512];
    const int t = threadIdx.x;
    const int d = t & 63, s = t >> 6;
    const int blk = blockIdx.x;
    if (blk < 256) {
        const int b = blk >> 3, jq = blk & 7;
        const int j = jq * 256 + t;
        float a = 0.f;
        for (int k = 0; k < 16; ++k)
            a += part[(size_t)(b * 16 + k) * HC_ + j];
        Gs[t] = a;
        __syncthreads();
        float acc = 0.f;
        const int j0 = jq * 256 + s * 64;
        for (int jj = 0; jj < 64; ++jj)
            acc = fmaf(Gs[s * 64 + jj],
                       w1[(size_t)(HC_ + j0 + jj) * D_ + d], acc);
        red[s * 64 + d] = acc;
        __syncthreads();
        if (s == 0)
            gpart[(size_t)blk * 64 + d] =
                red[d] + red[64 + d] + red[128 + d] + red[192 + d];
    } else {
        const int wq = blk - 256;
        const int c0 = wq * 256 + s * 64;
        float a = 0.f, c2 = 0.f;
        for (int c = c0; c < c0 + 64; ++c) {
            const float wvv = w1[(size_t)c * D_ + d];
            a = fmaf(lnw[c], wvv, a);
            c2 = fmaf(lnb[c], wvv, c2);
        }
        red[s * 64 + d] = a;
        red[256 + s * 64 + d] = c2;
        __syncthreads();
        if (s == 0) {
            Wpart[wq * 64 + d] =
                red[d] + red[64 + d] + red[128 + d] + red[192 + d];
            Bpart[wq * 64 + d] = red[256 + d] + red[320 + d]
                               + red[384 + d] + red[448 + d];
        }
    }
}

// ---------------------------------------------------------------------------
// K45: decision (with k2b folded in) + masked copy.  One wave per token.
// W1s/Bs/gterm computed inline from Wpart/Bpart/gpart (24 L2-hot loads).
// Dropped tokens write zeros WITHOUT reading x.  grid 8192, block 256.
// ---------------------------------------------------------------------------
__global__ __launch_bounds__(256) void k45_decide_mask(
        const float* __restrict__ Pp, const float* __restrict__ muv,
        const float* __restrict__ rsv, const float* __restrict__ gpart,
        const float* __restrict__ Wpart, const float* __restrict__ Bpart,
        const float* __restrict__ b1, const float* __restrict__ w2,
        const float* __restrict__ b2, const float* __restrict__ gum,
        const float* __restrict__ x, float* __restrict__ out) {
    const int t = threadIdx.x;
    const int lane = t & 63, w = t >> 6;
    const int token = blockIdx.x * 4 + w;
    const int b = token >> 10;

    // ---- folded k2b: W1s/Bs/gterm for this lane ----
    float W1 = 0.f, Bsv = 0.f, gt = 0.f;
#pragma unroll
    for (int q = 0; q < 8; ++q) {
        W1 += Wpart[q * 64 + lane];
        Bsv += Bpart[q * 64 + lane];
        gt += gpart[(size_t)(b * 8 + q) * 64 + lane];
    }
    gt *= (1.f / N_);

    const float2 gv = *reinterpret_cast<const float2*>(gum + token * 2);
    const float p = Pp[(size_t)token * D_ + lane];
    const float mu = muv[token], rs = rsv[token];
    float h = rs * (p - mu * W1) + Bsv + gt + b1[lane];
    h = 0.5f * h * (1.f + erff(h * 0.70710678118654752f));   // exact gelu
    const float2 w2v = *reinterpret_cast<const float2*>(w2 + lane * 2);
    float l0 = h * w2v.x;
    float l1 = h * w2v.y;
#pragma unroll
    for (int o = 1; o < 64; o <<= 1) {
        l0 += __shfl_xor(l0, o);
        l1 += __shfl_xor(l1, o);
    }
    const float z0 = l0 + b2[0] + gv.x;
    const float z1 = l1 + b2[1] + gv.y;

    float4* dst = reinterpret_cast<float4*>(out + (size_t)token * C_);
    if (z0 >= z1) {    // keep (argmax ties -> index 0): copy x
        const float4* src =
            reinterpret_cast<const float4*>(x + (size_t)token * C_);
#pragma unroll
        for (int c = 0; c < 16; ++c)
            dst[c * 64 + lane] = src[c * 64 + lane];
    } else {           // drop: write zeros, skip the x read
        const float4 z = make_float4(0.f, 0.f, 0.f, 0.f);
#pragma unroll
        for (int c = 0; c < 16; ++c)
            dst[c * 64 + lane] = z;
    }
}

// ---------------------------------------------------------------------------
extern "C" void kernel_launch(void* const* d_in, const int* in_sizes, int n_in,
                              void* d_out, int out_size, void* d_ws,
                              size_t ws_size, hipStream_t stream) {
    const float* x   = (const float*)d_in[0];
    const float* gum = (const float*)d_in[1];
    const float* lnw = (const float*)d_in[2];
    const float* lnb = (const float*)d_in[3];
    const float* w1  = (const float*)d_in[4];
    const float* b1  = (const float*)d_in[5];
    const float* w2  = (const float*)d_in[6];
    const float* b2  = (const float*)d_in[7];
    float* out = (float*)d_out;

    float* wsf   = (float*)d_ws;
    float* Pp    = wsf;                                   // 32768*64
    float* muv   = Pp + (size_t)NT_ * D_;                 // 32768
    float* rsv   = muv + NT_;                             // 32768
    float* part  = rsv + NT_;                             // 512*2048
    float* gpart = part + (size_t)512 * HC_;              // 256*64
    float* Wpart = gpart + 256 * 64;                      // 8*64
    float* Bpart = Wpart + 8 * 64;                        // 8*64

    mk1<<<512, 256, 0, stream>>>(x, lnw, lnb, w1, Pp, muv, rsv, part);
    k2a_part<<<264, 256, 0, stream>>>(part, w1, lnw, lnb,
                                      gpart, Wpart, Bpart);
    k45_decide_mask<<<NT_ / 4, 256, 0, stream>>>(Pp, muv, rsv, gpart,
                                                 Wpart, Bpart, b1, w2, b2,
                                                 gum, x, out);
}